// Round 7
// baseline (36.920 us; speedup 1.0000x reference)
//
#include <hip/hip_runtime.h>

// out[b,k] = sum_n exp(-2*pi*||dom_k - C[b,n]||^2)
// R7: MFMA computes the exact base-2 exponent e (R5's validated split-bf16
// encoding, UNSCALED, bit-identical to the R5 kernel that passed at 0.5).
// exp2(e) is then approximated on the VALU with Schraudolph in well-defined
// fp32 ops:  t = fma(e, 2^23, 2^23*126.9437); t = max(t,0); u = (u32)t;
// val = bitcast_f32(u).  4 VALU ops (8 cyc) per exp vs v_exp_f32's ~18.
//   e = px*x + py*y + pz*z + wn + dk, p=S1*d, wn=-S2*||c||^2, dk=-S2*||d||^2
// K-slot map (A=atom, B=dom):
//   lanes 0-31  (K0-7):  A={xh,yh,zh,wh,1,xl,yl,zl} B={pxh,pyh,pzh,1,dkh,pxh,pyh,pzh}
//   lanes 32-63 (K8-15): A={wl,1,xh,yh,zh,0,0,0}    B={1,dkl,pxl,pyl,pzl,0,0,0}
// Grid: 8 k-groups x 4 atom-quarters x 32 b = 1024 blocks x 512 thr, 32 KB LDS
// -> 4 blocks/CU, 32 waves/CU. Partials via atomicAdd after async memset.

#define NATOMS 4096
#define KTOT   2048
#define BLOCK  512
#define QATOMS 1024   // atoms per block (quarter)
#define ATILES 32     // 32-atom MFMA tiles per block

typedef float  f32x16 __attribute__((ext_vector_type(16)));
typedef __bf16 bf16x8 __attribute__((ext_vector_type(8)));

__global__ __launch_bounds__(BLOCK) void theta_layer_kernel(
        const float* __restrict__ C, const float* __restrict__ dom,
        float* __restrict__ out) {
    constexpr float S2     = 9.064720283654388f;   // 2*pi / ln(2)
    constexpr float S1     = 18.129440567308776f;  // 4*pi / ln(2)
    constexpr float SCALE  = 8388608.0f;           // 2^23
    constexpr float BIAS23 = 1064880937.0f;        // 2^23 * 126.9437

    __shared__ bf16x8 sA[ATILES * 64];  // 32 KB prepacked A-fragments

    const int tid  = threadIdx.x;
    const int lane = tid & 63;
    const int w    = tid >> 6;        // wave 0..7
    const int b    = blockIdx.y;
    const int kg   = blockIdx.x & 7;  // k-group
    const int q    = blockIdx.x >> 3; // atom quarter 0..3

    const __bf16 one = (__bf16)1.0f;
    const __bf16 zb  = (__bf16)0.0f;

    // ---- stage this quarter's atoms as A-fragments ----
    const float* Cq = C + ((size_t)b * NATOMS + (size_t)q * QATOMS) * 3;
    for (int j = tid; j < QATOMS; j += BLOCK) {
        float x = Cq[3 * j + 0];
        float y = Cq[3 * j + 1];
        float z = Cq[3 * j + 2];
        __bf16 xh = (__bf16)x; __bf16 xl = (__bf16)(x - (float)xh);
        __bf16 yh = (__bf16)y; __bf16 yl = (__bf16)(y - (float)yh);
        __bf16 zh = (__bf16)z; __bf16 zl = (__bf16)(z - (float)zh);
        float wn = -S2 * (x * x + y * y + z * z);
        __bf16 wh = (__bf16)wn; __bf16 wl = (__bf16)(wn - (float)wh);
        const int t = j >> 5, r = j & 31;
        bf16x8 f0 = {xh, yh, zh, wh, one, xl, yl, zl};  // K0-7  (lanes 0-31)
        bf16x8 f1 = {wl, one, xh, yh, zh, zb, zb, zb};  // K8-15 (lanes 32-63)
        sA[t * 64 + r]      = f0;
        sA[t * 64 + 32 + r] = f1;
    }

    // ---- per-wave B fragment (dom side), col k = lane&31 of k-tile kt ----
    const int kt = kg * 8 + w;                 // 0..63
    const int k  = kt * 32 + (lane & 31);
    const float dx = dom[3 * k + 0], dy = dom[3 * k + 1], dz = dom[3 * k + 2];
    const float px = S1 * dx, py = S1 * dy, pz = S1 * dz;
    __bf16 pxh = (__bf16)px; __bf16 pxl = (__bf16)(px - (float)pxh);
    __bf16 pyh = (__bf16)py; __bf16 pyl = (__bf16)(py - (float)pyh);
    __bf16 pzh = (__bf16)pz; __bf16 pzl = (__bf16)(pz - (float)pzh);
    const float dkf = -S2 * (dx * dx + dy * dy + dz * dz);
    __bf16 dkh = (__bf16)dkf; __bf16 dkl = (__bf16)(dkf - (float)dkh);

    bf16x8 bfrag;
    if (lane < 32) {
        bf16x8 t0 = {pxh, pyh, pzh, one, dkh, pxh, pyh, pzh};  // K0-7
        bfrag = t0;
    } else {
        bf16x8 t1 = {one, dkl, pxl, pyl, pzl, zb, zb, zb};     // K8-15
        bfrag = t1;
    }

    __syncthreads();

    // ---- main loop: ds_read_b128 + mfma -> 16x (fma + max + cvt + add) ----
    const f32x16 zero = {};
    float a0 = 0.f, a1 = 0.f, a2 = 0.f, a3 = 0.f;
    #pragma unroll 2
    for (int t = 0; t < ATILES; ++t) {
        bf16x8 af = sA[t * 64 + lane];
        f32x16 d = __builtin_amdgcn_mfma_f32_32x32x16_bf16(af, bfrag, zero, 0, 0, 0);
        #pragma unroll
        for (int i = 0; i < 4; ++i) {
            float t0 = fmaxf(fmaf(d[i],      SCALE, BIAS23), 0.0f);
            float t1 = fmaxf(fmaf(d[i + 4],  SCALE, BIAS23), 0.0f);
            float t2 = fmaxf(fmaf(d[i + 8],  SCALE, BIAS23), 0.0f);
            float t3 = fmaxf(fmaf(d[i + 12], SCALE, BIAS23), 0.0f);
            a0 += __uint_as_float((unsigned)t0);
            a1 += __uint_as_float((unsigned)t1);
            a2 += __uint_as_float((unsigned)t2);
            a3 += __uint_as_float((unsigned)t3);
        }
    }
    float acc = (a0 + a1) + (a2 + a3);

    // ---- combine row-halves (lane ^ 32), emit partial ----
    float other = __shfl_xor(acc, 32, 64);
    float tot = acc + other;
    if (lane < 32) {
        atomicAdd(&out[(size_t)b * KTOT + k], tot);
    }
}

extern "C" void kernel_launch(void* const* d_in, const int* in_sizes, int n_in,
                              void* d_out, int out_size, void* d_ws, size_t ws_size,
                              hipStream_t stream) {
    const float* C   = (const float*)d_in[0];
    const float* dom = (const float*)d_in[1];
    float* out       = (float*)d_out;
    const int B = in_sizes[0] / (NATOMS * 3);  // 32
    hipMemsetAsync(out, 0, (size_t)out_size * sizeof(float), stream);
    dim3 grid(32, B);  // (8 k-groups x 4 atom-quarters) x B
    theta_layer_kernel<<<grid, BLOCK, 0, stream>>>(C, dom, out);
}

// Round 8
// 36.398 us; speedup vs baseline: 1.0143x; 1.0143x over previous
//
#include <hip/hip_runtime.h>

// out[b,k] = sum_n exp(-2*pi*||dom_k - C[b,n]||^2)
// R8: same math as R7 (MFMA split-bf16 exponent + Schraudolph exp on VALU),
// restructured so each block OWNS its output slice: no atomics, no memset.
//   - grid = 8 k-groups x 32 b = 256 blocks (1/CU), 512 threads (8 waves)
//   - wave w handles k-tile kg*8+w (32 k), loops over ALL 128 atom tiles
//   - full C[b] staged once in LDS as prepacked A-fragments (128 KB)
//   - exp2(e) ~= bitcast_f32((u32)max(fma(e, 2^23, 2^23*126.9437), 0))
// K-slot map (A=atom, B=dom):
//   lanes 0-31  (K0-7):  A={xh,yh,zh,wh,1,xl,yl,zl} B={pxh,pyh,pzh,1,dkh,pxh,pyh,pzh}
//   lanes 32-63 (K8-15): A={wl,1,xh,yh,zh,0,0,0}    B={1,dkl,pxl,pyl,pzl,0,0,0}

#define NATOMS 4096
#define KTOT   2048
#define BLOCK  512
#define ATILES 128    // 32-atom MFMA tiles per block (all atoms)

typedef float  f32x16 __attribute__((ext_vector_type(16)));
typedef __bf16 bf16x8 __attribute__((ext_vector_type(8)));

__global__ __launch_bounds__(BLOCK) void theta_layer_kernel(
        const float* __restrict__ C, const float* __restrict__ dom,
        float* __restrict__ out) {
    constexpr float S2     = 9.064720283654388f;   // 2*pi / ln(2)
    constexpr float S1     = 18.129440567308776f;  // 4*pi / ln(2)
    constexpr float SCALE  = 8388608.0f;           // 2^23
    constexpr float BIAS23 = 1064880937.0f;        // 2^23 * 126.9437

    __shared__ bf16x8 sA[ATILES * 64];  // 128 KB prepacked A-fragments

    const int tid  = threadIdx.x;
    const int lane = tid & 63;
    const int w    = tid >> 6;        // wave 0..7
    const int b    = blockIdx.y;
    const int kg   = blockIdx.x;      // k-group 0..7

    const __bf16 one = (__bf16)1.0f;
    const __bf16 zb  = (__bf16)0.0f;

    // ---- stage ALL of C[b] as A-fragments (8 atoms/thread) ----
    const float* Cb = C + (size_t)b * NATOMS * 3;
    for (int j = tid; j < NATOMS; j += BLOCK) {
        float x = Cb[3 * j + 0];
        float y = Cb[3 * j + 1];
        float z = Cb[3 * j + 2];
        __bf16 xh = (__bf16)x; __bf16 xl = (__bf16)(x - (float)xh);
        __bf16 yh = (__bf16)y; __bf16 yl = (__bf16)(y - (float)yh);
        __bf16 zh = (__bf16)z; __bf16 zl = (__bf16)(z - (float)zh);
        float wn = -S2 * (x * x + y * y + z * z);
        __bf16 wh = (__bf16)wn; __bf16 wl = (__bf16)(wn - (float)wh);
        const int t = j >> 5, r = j & 31;
        bf16x8 f0 = {xh, yh, zh, wh, one, xl, yl, zl};  // K0-7  (lanes 0-31)
        bf16x8 f1 = {wl, one, xh, yh, zh, zb, zb, zb};  // K8-15 (lanes 32-63)
        sA[t * 64 + r]      = f0;
        sA[t * 64 + 32 + r] = f1;
    }

    // ---- per-wave B fragment (dom side), col k = lane&31 of k-tile kt ----
    const int kt = kg * 8 + w;                 // 0..63
    const int k  = kt * 32 + (lane & 31);
    const float dx = dom[3 * k + 0], dy = dom[3 * k + 1], dz = dom[3 * k + 2];
    const float px = S1 * dx, py = S1 * dy, pz = S1 * dz;
    __bf16 pxh = (__bf16)px; __bf16 pxl = (__bf16)(px - (float)pxh);
    __bf16 pyh = (__bf16)py; __bf16 pyl = (__bf16)(py - (float)pyh);
    __bf16 pzh = (__bf16)pz; __bf16 pzl = (__bf16)(pz - (float)pzh);
    const float dkf = -S2 * (dx * dx + dy * dy + dz * dz);
    __bf16 dkh = (__bf16)dkf; __bf16 dkl = (__bf16)(dkf - (float)dkh);

    bf16x8 bfrag;
    if (lane < 32) {
        bf16x8 t0 = {pxh, pyh, pzh, one, dkh, pxh, pyh, pzh};  // K0-7
        bfrag = t0;
    } else {
        bf16x8 t1 = {one, dkl, pxl, pyl, pzl, zb, zb, zb};     // K8-15
        bfrag = t1;
    }

    __syncthreads();

    // ---- main loop: ds_read_b128 + mfma -> 16x (fma + max + cvt + add) ----
    const f32x16 zero = {};
    float a0 = 0.f, a1 = 0.f, a2 = 0.f, a3 = 0.f;
    #pragma unroll 2
    for (int t = 0; t < ATILES; ++t) {
        bf16x8 af = sA[t * 64 + lane];
        f32x16 d = __builtin_amdgcn_mfma_f32_32x32x16_bf16(af, bfrag, zero, 0, 0, 0);
        #pragma unroll
        for (int i = 0; i < 4; ++i) {
            float t0 = fmaxf(fmaf(d[i],      SCALE, BIAS23), 0.0f);
            float t1 = fmaxf(fmaf(d[i + 4],  SCALE, BIAS23), 0.0f);
            float t2 = fmaxf(fmaf(d[i + 8],  SCALE, BIAS23), 0.0f);
            float t3 = fmaxf(fmaf(d[i + 12], SCALE, BIAS23), 0.0f);
            a0 += __uint_as_float((unsigned)t0);
            a1 += __uint_as_float((unsigned)t1);
            a2 += __uint_as_float((unsigned)t2);
            a3 += __uint_as_float((unsigned)t3);
        }
    }
    float acc = (a0 + a1) + (a2 + a3);

    // ---- combine row-halves (lane ^ 32), direct store (exclusive owner) ----
    float other = __shfl_xor(acc, 32, 64);
    float tot = acc + other;
    if (lane < 32) {
        out[(size_t)b * KTOT + k] = tot;
    }
}

extern "C" void kernel_launch(void* const* d_in, const int* in_sizes, int n_in,
                              void* d_out, int out_size, void* d_ws, size_t ws_size,
                              hipStream_t stream) {
    const float* C   = (const float*)d_in[0];
    const float* dom = (const float*)d_in[1];
    float* out       = (float*)d_out;
    const int B = in_sizes[0] / (NATOMS * 3);  // 32
    dim3 grid(8, B);  // 8 k-groups x B, each block owns 256 k outputs
    theta_layer_kernel<<<grid, BLOCK, 0, stream>>>(C, dom, out);
}

// Round 9
// 34.273 us; speedup vs baseline: 1.0772x; 1.0620x over previous
//
#include <hip/hip_runtime.h>

// out[b,k] = sum_n exp(-2*pi*||dom_k - C[b,n]||^2)
// R9: R8's exclusive-ownership structure (no atomics, no memset) at 2x the
// occupancy: 1024-thread blocks (16 waves), 1 block/CU, 4 waves/SIMD.
// Two waves split each k-tile's atom range; 2 KB LDS reduce at the end.
//   - MFMA (v_mfma_f32_32x32x16_bf16, split-bf16 encoding) emits exact
//     base-2 exponent e; VALU does Schraudolph exp2:
//     val = bitcast_f32((u32)max(fma(e, 2^23, 2^23*126.9437), 0))  [4 ops]
// K-slot map (A=atom, B=dom):
//   lanes 0-31  (K0-7):  A={xh,yh,zh,wh,1,xl,yl,zl} B={pxh,pyh,pzh,1,dkh,pxh,pyh,pzh}
//   lanes 32-63 (K8-15): A={wl,1,xh,yh,zh,0,0,0}    B={1,dkl,pxl,pyl,pzl,0,0,0}

#define NATOMS 4096
#define KTOT   2048
#define BLOCK  1024
#define ATILES 128    // 32-atom MFMA tiles (all atoms staged once)
#define TPW    64     // tiles per wave (half of ATILES)

typedef float  f32x16 __attribute__((ext_vector_type(16)));
typedef __bf16 bf16x8 __attribute__((ext_vector_type(8)));

__global__ __launch_bounds__(BLOCK) void theta_layer_kernel(
        const float* __restrict__ C, const float* __restrict__ dom,
        float* __restrict__ out) {
    constexpr float S2     = 9.064720283654388f;   // 2*pi / ln(2)
    constexpr float S1     = 18.129440567308776f;  // 4*pi / ln(2)
    constexpr float SCALE  = 8388608.0f;           // 2^23
    constexpr float BIAS23 = 1064880937.0f;        // 2^23 * 126.9437

    __shared__ bf16x8 sA[ATILES * 64];  // 128 KB prepacked A-fragments

    const int tid  = threadIdx.x;
    const int lane = tid & 63;
    const int w    = tid >> 6;        // wave 0..15
    const int b    = blockIdx.y;
    const int kg   = blockIdx.x;      // k-group 0..7

    const __bf16 one = (__bf16)1.0f;
    const __bf16 zb  = (__bf16)0.0f;

    // ---- stage ALL of C[b] as A-fragments (4 atoms/thread) ----
    const float* Cb = C + (size_t)b * NATOMS * 3;
    for (int j = tid; j < NATOMS; j += BLOCK) {
        float x = Cb[3 * j + 0];
        float y = Cb[3 * j + 1];
        float z = Cb[3 * j + 2];
        __bf16 xh = (__bf16)x; __bf16 xl = (__bf16)(x - (float)xh);
        __bf16 yh = (__bf16)y; __bf16 yl = (__bf16)(y - (float)yh);
        __bf16 zh = (__bf16)z; __bf16 zl = (__bf16)(z - (float)zh);
        float wn = -S2 * (x * x + y * y + z * z);
        __bf16 wh = (__bf16)wn; __bf16 wl = (__bf16)(wn - (float)wh);
        const int t = j >> 5, r = j & 31;
        bf16x8 f0 = {xh, yh, zh, wh, one, xl, yl, zl};  // K0-7  (lanes 0-31)
        bf16x8 f1 = {wl, one, xh, yh, zh, zb, zb, zb};  // K8-15 (lanes 32-63)
        sA[t * 64 + r]      = f0;
        sA[t * 64 + 32 + r] = f1;
    }

    // ---- per-wave B fragment: k-tile kt = kg*8 + (w&7), col = lane&31 ----
    const int kt = kg * 8 + (w & 7);           // 0..63
    const int k  = kt * 32 + (lane & 31);
    const float dx = dom[3 * k + 0], dy = dom[3 * k + 1], dz = dom[3 * k + 2];
    const float px = S1 * dx, py = S1 * dy, pz = S1 * dz;
    __bf16 pxh = (__bf16)px; __bf16 pxl = (__bf16)(px - (float)pxh);
    __bf16 pyh = (__bf16)py; __bf16 pyl = (__bf16)(py - (float)pyh);
    __bf16 pzh = (__bf16)pz; __bf16 pzl = (__bf16)(pz - (float)pzh);
    const float dkf = -S2 * (dx * dx + dy * dy + dz * dz);
    __bf16 dkh = (__bf16)dkf; __bf16 dkl = (__bf16)(dkf - (float)dkh);

    bf16x8 bfrag;
    if (lane < 32) {
        bf16x8 t0 = {pxh, pyh, pzh, one, dkh, pxh, pyh, pzh};  // K0-7
        bfrag = t0;
    } else {
        bf16x8 t1 = {one, dkl, pxl, pyl, pzl, zb, zb, zb};     // K8-15
        bfrag = t1;
    }

    __syncthreads();

    // ---- main loop over this wave's half of the atom tiles ----
    const f32x16 zero = {};
    float a0 = 0.f, a1 = 0.f, a2 = 0.f, a3 = 0.f;
    const int t0i = (w >> 3) * TPW;   // waves 0-7: tiles 0-63; waves 8-15: 64-127
    #pragma unroll 2
    for (int t = t0i; t < t0i + TPW; ++t) {
        bf16x8 af = sA[t * 64 + lane];
        f32x16 d = __builtin_amdgcn_mfma_f32_32x32x16_bf16(af, bfrag, zero, 0, 0, 0);
        #pragma unroll
        for (int i = 0; i < 4; ++i) {
            float u0 = fmaxf(fmaf(d[i],      SCALE, BIAS23), 0.0f);
            float u1 = fmaxf(fmaf(d[i + 4],  SCALE, BIAS23), 0.0f);
            float u2 = fmaxf(fmaf(d[i + 8],  SCALE, BIAS23), 0.0f);
            float u3 = fmaxf(fmaf(d[i + 12], SCALE, BIAS23), 0.0f);
            a0 += __uint_as_float((unsigned)u0);
            a1 += __uint_as_float((unsigned)u1);
            a2 += __uint_as_float((unsigned)u2);
            a3 += __uint_as_float((unsigned)u3);
        }
    }
    float acc = (a0 + a1) + (a2 + a3);

    // ---- combine row-halves (lane ^ 32) ----
    float other = __shfl_xor(acc, 32, 64);
    float tot = acc + other;

    // ---- combine the two waves per k-tile via LDS (reuse sA), store ----
    __syncthreads();  // all reads of sA done
    float* red = (float*)sA;  // [16 waves][32 k]
    if (lane < 32) red[w * 32 + lane] = tot;
    __syncthreads();
    if (tid < 256) {
        const int t2 = tid >> 5;   // k-tile slot 0..7
        const int kc = tid & 31;
        float s = red[t2 * 32 + kc] + red[(t2 + 8) * 32 + kc];
        out[(size_t)b * KTOT + (kg * 8 + t2) * 32 + kc] = s;
    }
}

extern "C" void kernel_launch(void* const* d_in, const int* in_sizes, int n_in,
                              void* d_out, int out_size, void* d_ws, size_t ws_size,
                              hipStream_t stream) {
    const float* C   = (const float*)d_in[0];
    const float* dom = (const float*)d_in[1];
    float* out       = (float*)d_out;
    const int B = in_sizes[0] / (NATOMS * 3);  // 32
    dim3 grid(8, B);  // 8 k-groups x B, each block owns 256 k outputs
    theta_layer_kernel<<<grid, BLOCK, 0, stream>>>(C, dom, out);
}